// Round 6
// baseline (1839.120 us; speedup 1.0000x reference)
//
#include <hip/hip_runtime.h>
#include <cstddef>
#include <cstdint>

#define NN 200000
#define NINT 25000   // nodes 0..24999 have children

typedef _Float16 f16;
typedef __attribute__((ext_vector_type(8))) f16 f16x8;
typedef __attribute__((ext_vector_type(4))) float f32x4;

#define MFMA16(a,b,c) __builtin_amdgcn_mfma_f32_16x16x32_f16((a),(b),(c),0,0,0)

union H8 { uint4 u; f16 f[8]; f16x8 v; };
union F4 { float4 v; float f[4]; uint4 u; };

__device__ __forceinline__ float fsig(float v){ return __builtin_amdgcn_rcpf(1.f+__expf(-v)); }
__device__ __forceinline__ float ftanh(float v){ return 1.f-2.f*__builtin_amdgcn_rcpf(1.f+__expf(2.f*v)); }
// fp16 split-2: v = hi + lo/4096 + O(2^-24 |v|)
__device__ __forceinline__ void split2(float v, f16&h, f16&l){ h=(f16)v; l=(f16)((v-(float)h)*4096.f); }

// ---------------------------------------------------------------------------
// weight [K][N] fp32 -> frag layout ((k>>3)*N + n)*8 + (k&7), hi/lo f16
// ---------------------------------------------------------------------------
__global__ void split_w_kernel(const float* __restrict__ src,
                               f16* __restrict__ dh, f16* __restrict__ dl, int K, int N)
{
    int e = blockIdx.x*256 + threadIdx.x;
    if (e >= K*N) return;
    int k = e / N, n = e - k*N;
    f16 hh, ll; split2(src[e], hh, ll);
    int o = ((k>>3)*N + n)*8 + (k&7);
    dh[o]=hh; dl[o]=ll;
}

// ---------------------------------------------------------------------------
// iou_pc: producer-consumer persistent GEMM vs a 768-col weight (K=256).
//   MODE 0: childless nodes.  B = x[node] fp32.   Epilogue: LSTM (fc=0) -> c,h
//   MODE 1: internal parents. B = ht[node-base].  Epilogue: LSTM with
//           x_iou[node] + fc[node-base] -> c,h
//   MODE 2: x_iou precompute. B = x[node].        GEMM stores preact+bias.
// Block = 7 waves: w<6 GEMM (gate g=w>>1, slice s=w&1 -> 32 d per class,
// 8 classes), w==6 producer (stage fp32->split LDS; run epilogue).
// One barrier/tile; acts & preacts double-buffered; XOR-swizzled LDS.
// ---------------------------------------------------------------------------
template<int MODE>
__launch_bounds__(448, 4)
__global__ void iou_pc(const float* __restrict__ bsrc,
                       const f16* __restrict__ wh, const f16* __restrict__ wl,
                       const float* __restrict__ b_iou,
                       const float* __restrict__ xiR, const float* __restrict__ fcR,
                       float* __restrict__ xiW,
                       float* __restrict__ cW, float* __restrict__ hW,
                       int base, int pend, int ntiles, int nch)
{
    __shared__ f16 AhL[8192];   // 2 x [16 rows][256 k]
    __shared__ f16 AlL[8192];
    __shared__ float PL[3072];  // 2 x [6 waves][16 nodes][16 d]

    const int cls = blockIdx.x / nch;        // 0..7 (d-class)
    const int chunk = blockIdx.x % nch;      // XCD = chunk % 8
    const int tpc = (ntiles + nch - 1) / nch;
    const int t0 = chunk * tpc;
    const int T = min(ntiles, t0 + tpc) - t0;
    if (T <= 0) return;

    const int t = threadIdx.x, lane = t & 63, w = t >> 6;
    const int c15 = lane & 15, qq = lane >> 4;
    const float INV = 1.f / 4096.f;

    // ---- resident weights (GEMM waves): 16 cols, hi+lo = 64 VGPR ----
    f16x8 wHr[8], wLr[8];
    F4 bw;                        // MODE 2 gemm bias
    if (w < 6) {
        const int g = w >> 1, sl = w & 1;
        const int col = g*256 + cls*32 + sl*16 + c15;
#pragma unroll
        for (int ch = 0; ch < 8; ++ch) {
            size_t ao = ((size_t)(ch*4 + qq)*768 + col)*8;
            wHr[ch] = *(const f16x8*)(wh + ao);
            wLr[ch] = *(const f16x8*)(wl + ao);
        }
        if (MODE == 2)
            bw.v = *(const float4*)(b_iou + g*256 + cls*32 + sl*16 + qq*4);
    }
    F4 pbias[6];                  // MODE 0 producer biases [g*2+s]
    if (MODE == 0 && w == 6) {
#pragma unroll
        for (int g = 0; g < 3; ++g)
#pragma unroll
            for (int sl = 0; sl < 2; ++sl)
                pbias[g*2+sl].v = *(const float4*)(b_iou + g*256 + cls*32 + sl*16 + qq*4);
    }

    // ---------------- producer helpers ----------------
    auto STAGE = [&](int m, int buf) {
        const int node = base + m*16 + c15;
        const int brow = (MODE == 1) ? (node - base) : node;
        const bool v = node < pend;
        const float* bp = bsrc + (size_t)brow*256 + qq*64;
#pragma unroll
        for (int half = 0; half < 2; ++half) {
            uint4 r[8];
#pragma unroll
            for (int i = 0; i < 8; ++i)
                r[i] = v ? *(const uint4*)(bp + half*32 + i*4) : (uint4){0,0,0,0};
#pragma unroll
            for (int ii = 0; ii < 4; ++ii) {
                F4 a, b; a.u = r[2*ii]; b.u = r[2*ii+1];
                H8 hi, lo;
#pragma unroll
                for (int e = 0; e < 4; ++e) {
                    split2(a.f[e], hi.f[e],   lo.f[e]);
                    split2(b.f[e], hi.f[4+e], lo.f[4+e]);
                }
                int k = qq*64 + half*32 + ii*8;
                int idx = buf*4096 + ((c15*256 + k) ^ ((c15 & 7) << 3));
                *(uint4*)&AhL[idx] = hi.u;
                *(uint4*)&AlL[idx] = lo.u;
            }
        }
    };

    auto EPI = [&](int m, int pbuf) {
        const int node = base + m*16 + c15;
        if (node >= pend) return;
        const int pb_ = pbuf*1536;
        const int sw = ((c15*16 + qq*4) ^ ((c15 & 7) << 2));
        const size_t no = (size_t)node*256;
#pragma unroll
        for (int sl = 0; sl < 2; ++sl) {
            F4 ig, og, ug, fcv;
            ig.v = *(const float4*)&PL[pb_ + (0+sl)*256 + sw];
            og.v = *(const float4*)&PL[pb_ + (2+sl)*256 + sw];
            ug.v = *(const float4*)&PL[pb_ + (4+sl)*256 + sw];
            const int dcol = cls*32 + sl*16 + qq*4;
            if (MODE == 0) {
#pragma unroll
                for (int j = 0; j < 4; ++j) {
                    ig.f[j] += pbias[0+sl].f[j];
                    og.f[j] += pbias[2+sl].f[j];
                    ug.f[j] += pbias[4+sl].f[j];
                }
                fcv.v = (float4){0,0,0,0};
            } else {
                const float* xr = xiR + (size_t)node*768;
                F4 x0, x1, x2;
                x0.v = *(const float4*)(xr + dcol);
                x1.v = *(const float4*)(xr + 256 + dcol);
                x2.v = *(const float4*)(xr + 512 + dcol);
                fcv.v = *(const float4*)(fcR + (size_t)(node - base)*256 + dcol);
#pragma unroll
                for (int j = 0; j < 4; ++j) {
                    ig.f[j] += x0.f[j]; og.f[j] += x1.f[j]; ug.f[j] += x2.f[j];
                }
            }
            F4 cn, hn;
#pragma unroll
            for (int j = 0; j < 4; ++j) {
                float cc = fsig(ig.f[j]) * ftanh(ug.f[j]) + fcv.f[j];
                hn.f[j] = fsig(og.f[j]) * ftanh(cc);
                cn.f[j] = cc;
            }
            *(float4*)(cW + no + dcol) = cn.v;
            *(float4*)(hW + no + dcol) = hn.v;
        }
    };

    // ---------------- pipeline ----------------
    if (w == 6) STAGE(t0, 0);
    __syncthreads();
    for (int j = 0; j < T; ++j) {
        const int buf = j & 1;
        if (w < 6) {
            f32x4 aH = {0,0,0,0}, aL = {0,0,0,0};
            const int abase = buf*4096;
#pragma unroll
            for (int ch = 0; ch < 8; ++ch) {
                int idx = abase + ((c15*256 + ch*32 + qq*8) ^ ((c15 & 7) << 3));
                f16x8 bh = *(const f16x8*)&AhL[idx];
                f16x8 bl = *(const f16x8*)&AlL[idx];
                aH = MFMA16(wHr[ch], bh, aH);
                aL = MFMA16(wHr[ch], bl, aL);
                aL = MFMA16(wLr[ch], bh, aL);
            }
            F4 r;
#pragma unroll
            for (int jj = 0; jj < 4; ++jj) r.f[jj] = aH[jj] + aL[jj]*INV;
            if (MODE == 2) {
                const int node = base + (t0 + j)*16 + c15;
                if (node < pend) {
                    const int g = w >> 1, sl = w & 1;
                    F4 o;
#pragma unroll
                    for (int jj = 0; jj < 4; ++jj) o.f[jj] = r.f[jj] + bw.f[jj];
                    *(float4*)(xiW + (size_t)node*768 + g*256 + cls*32 + sl*16 + qq*4) = o.v;
                }
            } else {
                int pidx = buf*1536 + w*256 + ((c15*16 + qq*4) ^ ((c15 & 7) << 2));
                *(float4*)&PL[pidx] = r.v;
            }
        } else {
            if (j + 1 < T) STAGE(t0 + j + 1, buf ^ 1);
            if (MODE != 2 && j > 0) EPI(t0 + j - 1, buf ^ 1);
        }
        __syncthreads();
    }
    if (MODE != 2 && w == 6) EPI(t0 + T - 1, (T - 1) & 1);
}

// ---------------------------------------------------------------------------
// f_pc: producer-consumer persistent GEMM vs a 256-col weight (K=256).
//   FMODE 0: xf precompute.  B = x[node], nodes [0,NINT). Store preact+b_f.
//   FMODE 1: child pass.     B = h[child]. GEMM epilogue: f=sigm(acc+xf[par]),
//            fc[par] = shfl-sum f*c; producer also writes ht[par] = sum h.
// Block = 5 waves: w<4 GEMM (cols cls*64 + w*16, 4 classes), w==4 producer.
// ---------------------------------------------------------------------------
template<int FMODE>
__launch_bounds__(320, 4)
__global__ void f_pc(const float* __restrict__ bsrc,
                     const f16* __restrict__ wh, const f16* __restrict__ wl,
                     const float* __restrict__ b_f,
                     const float* __restrict__ xfR, const float* __restrict__ cR,
                     float* __restrict__ xfW,
                     float* __restrict__ fcW, float* __restrict__ htW,
                     int cs, int ce, int pp, int ntiles, int nch)
{
    __shared__ f16 AhL[8192];
    __shared__ f16 AlL[8192];

    const int cls = blockIdx.x / nch;        // 0..3
    const int chunk = blockIdx.x % nch;
    const int tpc = (ntiles + nch - 1) / nch;
    const int t0 = chunk * tpc;
    const int T = min(ntiles, t0 + tpc) - t0;
    if (T <= 0) return;

    const int t = threadIdx.x, lane = t & 63, w = t >> 6;
    const int c15 = lane & 15, qq = lane >> 4;
    const float INV = 1.f / 4096.f;

    f16x8 wHr[8], wLr[8];
    F4 bf4;
    if (w < 4) {
        const int col = cls*64 + w*16 + c15;
#pragma unroll
        for (int ch = 0; ch < 8; ++ch) {
            size_t ao = ((size_t)(ch*4 + qq)*256 + col)*8;
            wHr[ch] = *(const f16x8*)(wh + ao);
            wLr[ch] = *(const f16x8*)(wl + ao);
        }
        if (FMODE == 0)
            bf4.v = *(const float4*)(b_f + cls*64 + w*16 + qq*4);
    }

    auto STAGE = [&](int m, int buf) {
        const int child = cs + m*16 + c15;
        const bool v = child < ce;
        const float* bp = bsrc + (size_t)child*256 + qq*64;
#pragma unroll
        for (int half = 0; half < 2; ++half) {
            uint4 r[8];
#pragma unroll
            for (int i = 0; i < 8; ++i)
                r[i] = v ? *(const uint4*)(bp + half*32 + i*4) : (uint4){0,0,0,0};
            if (FMODE == 1) {
                // ht = sum of h over sibling groups (c15 groups of 8)
#pragma unroll
                for (int i = 0; i < 8; ++i) {
                    F4 s; s.u = r[i];
#pragma unroll
                    for (int jj = 0; jj < 4; ++jj) {
                        s.f[jj] += __shfl_xor(s.f[jj], 1);
                        s.f[jj] += __shfl_xor(s.f[jj], 2);
                        s.f[jj] += __shfl_xor(s.f[jj], 4);
                    }
                    if (((c15 & 7) == 0) && v) {
                        const int par = (child - 1) >> 3;
                        *(float4*)(htW + (size_t)(par - pp)*256 + qq*64 + half*32 + i*4) = s.v;
                    }
                }
            }
#pragma unroll
            for (int ii = 0; ii < 4; ++ii) {
                F4 a, b; a.u = r[2*ii]; b.u = r[2*ii+1];
                H8 hi, lo;
#pragma unroll
                for (int e = 0; e < 4; ++e) {
                    split2(a.f[e], hi.f[e],   lo.f[e]);
                    split2(b.f[e], hi.f[4+e], lo.f[4+e]);
                }
                int k = qq*64 + half*32 + ii*8;
                int idx = buf*4096 + ((c15*256 + k) ^ ((c15 & 7) << 3));
                *(uint4*)&AhL[idx] = hi.u;
                *(uint4*)&AlL[idx] = lo.u;
            }
        }
    };

    if (w == 4) STAGE(t0, 0);
    __syncthreads();
    for (int j = 0; j < T; ++j) {
        const int buf = j & 1;
        if (w < 4) {
            f32x4 aH = {0,0,0,0}, aL = {0,0,0,0};
            const int abase = buf*4096;
#pragma unroll
            for (int ch = 0; ch < 8; ++ch) {
                int idx = abase + ((c15*256 + ch*32 + qq*8) ^ ((c15 & 7) << 3));
                f16x8 bh = *(const f16x8*)&AhL[idx];
                f16x8 bl = *(const f16x8*)&AlL[idx];
                aH = MFMA16(wHr[ch], bh, aH);
                aL = MFMA16(wHr[ch], bl, aL);
                aL = MFMA16(wLr[ch], bh, aL);
            }
            const int node = cs + (t0 + j)*16 + c15;
            const bool v = node < ce;
            const int dcol = cls*64 + w*16 + qq*4;
            if (FMODE == 0) {
                if (v) {
                    F4 o;
#pragma unroll
                    for (int jj = 0; jj < 4; ++jj)
                        o.f[jj] = aH[jj] + aL[jj]*INV + bf4.f[jj];
                    *(float4*)(xfW + (size_t)node*256 + dcol) = o.v;
                }
            } else {
                const int par = (node - 1) >> 3;
                F4 xf4, c4, q;
                xf4.v = v ? *(const float4*)(xfR + (size_t)par*256 + dcol) : (float4){0,0,0,0};
                c4.v  = v ? *(const float4*)(cR + (size_t)node*256 + dcol) : (float4){0,0,0,0};
#pragma unroll
                for (int jj = 0; jj < 4; ++jj) {
                    float f = fsig(aH[jj] + aL[jj]*INV + xf4.f[jj]);
                    q.f[jj] = v ? f * c4.f[jj] : 0.f;
                }
#pragma unroll
                for (int jj = 0; jj < 4; ++jj) {
                    q.f[jj] += __shfl_xor(q.f[jj], 1);
                    q.f[jj] += __shfl_xor(q.f[jj], 2);
                    q.f[jj] += __shfl_xor(q.f[jj], 4);
                }
                if (((c15 & 7) == 0) && v)
                    *(float4*)(fcW + (size_t)(par - pp)*256 + dcol) = q.v;
            }
        } else {
            if (j + 1 < T) STAGE(t0 + j + 1, buf ^ 1);
        }
        __syncthreads();
    }
}

// ---------------------------------------------------------------------------

extern "C" void kernel_launch(void* const* d_in, const int* in_sizes, int n_in,
                              void* d_out, int out_size, void* d_ws, size_t ws_size,
                              hipStream_t stream)
{
    const float* x     = (const float*)d_in[0];
    const float* W_iou = (const float*)d_in[1];
    const float* U_iou = (const float*)d_in[2];
    const float* b_iou = (const float*)d_in[3];
    const float* W_f   = (const float*)d_in[4];
    const float* U_f   = (const float*)d_in[5];
    const float* b_f   = (const float*)d_in[6];

    float* h = (float*)d_out;

    char* p = (char*)d_ws;
    float* c     = (float*)p;  p += (size_t)NN * 256 * 4;
    float* fc    = (float*)p;  p += (size_t)20320 * 256 * 4;
    float* ht    = (float*)p;  p += (size_t)20320 * 256 * 4;
    float* xf    = (float*)p;  p += (size_t)NINT * 256 * 4;
    float* x_iou = (float*)p;  p += (size_t)NINT * 768 * 4;
    f16* wfh = (f16*)p;  p += 65536  * 2;
    f16* wfl = (f16*)p;  p += 65536  * 2;
    f16* ufh = (f16*)p;  p += 65536  * 2;
    f16* ufl = (f16*)p;  p += 65536  * 2;
    f16* wih = (f16*)p;  p += 196608 * 2;
    f16* wil = (f16*)p;  p += 196608 * 2;
    f16* uih = (f16*)p;  p += 196608 * 2;
    f16* uil = (f16*)p;  p += 196608 * 2;

    split_w_kernel<<<256, 256, 0, stream>>>(W_f,   wfh, wfl, 256, 256);
    split_w_kernel<<<256, 256, 0, stream>>>(U_f,   ufh, ufl, 256, 256);
    split_w_kernel<<<768, 256, 0, stream>>>(W_iou, wih, wil, 256, 768);
    split_w_kernel<<<768, 256, 0, stream>>>(U_iou, uih, uil, 256, 768);

    const int S_[8] = {0, 1, 9, 73, 585, 4681, 37449, 200000};
    auto cdiv = [](int a, int b){ return (a + b - 1) / b; };
    auto m8   = [](int v){ v = ((v + 7) / 8) * 8; return v < 8 ? 8 : v; };

    // xf = x @ W_f + b_f  for internal nodes
    {
        int tiles = cdiv(NINT, 16);
        int nch = m8(cdiv(tiles, 4)); if (nch > 192) nch = 192;
        f_pc<0><<<4*nch, 320, 0, stream>>>(x, wfh, wfl, b_f,
            nullptr, nullptr, xf, nullptr, nullptr, 0, NINT, 0, tiles, nch);
    }
    // x_iou = x @ W_iou + b_iou  for internal nodes
    {
        int tiles = cdiv(NINT, 16);
        int nch = m8(cdiv(tiles, 8)); if (nch > 64) nch = 64;
        iou_pc<2><<<8*nch, 448, 0, stream>>>(x, wih, wil, b_iou,
            nullptr, nullptr, x_iou, nullptr, nullptr, 0, NINT, tiles, nch);
    }
    // all childless nodes: full LSTM with fc = 0
    {
        int tiles = cdiv(NN - NINT, 16);
        int nch = 64;
        iou_pc<0><<<8*nch, 448, 0, stream>>>(x, wih, wil, b_iou,
            nullptr, nullptr, nullptr, c, h, NINT, NN, tiles, nch);
    }
    // levels 5..0: child pass (fc, ht) then internal-parent LSTM pass
    for (int l = 5; l >= 0; --l) {
        int ps = S_[l];
        int pe = (S_[l+1] < NINT) ? S_[l+1] : NINT;
        int cs = S_[l+1], ce = S_[l+2];

        int tiles_c = cdiv(ce - cs, 16);
        int nchc = m8(cdiv(tiles_c, 4)); if (nchc > 192) nchc = 192;
        f_pc<1><<<4*nchc, 320, 0, stream>>>(h, ufh, ufl, nullptr,
            xf, c, nullptr, fc, ht, cs, ce, ps, tiles_c, nchc);

        int tiles_p = cdiv(pe - ps, 16);
        int nchp = m8(cdiv(tiles_p, 8)); if (nchp > 64) nchp = 64;
        iou_pc<1><<<8*nchp, 448, 0, stream>>>(ht, uih, uil, nullptr,
            x_iou, fc, nullptr, c, h, ps, pe, tiles_p, nchp);
    }
}

// Round 7
// 1443.313 us; speedup vs baseline: 1.2742x; 1.2742x over previous
//
#include <hip/hip_runtime.h>
#include <cstddef>
#include <cstdint>

#define NN 200000
#define NINT 25000   // nodes 0..24999 have children

typedef _Float16 f16;
typedef __attribute__((ext_vector_type(8))) f16 f16x8;
typedef __attribute__((ext_vector_type(4))) float f32x4;

#define MFMA16(a,b,c) __builtin_amdgcn_mfma_f32_16x16x32_f16((a),(b),(c),0,0,0)

union H8 { uint4 u; f16 f[8]; f16x8 v; };
union F4 { float4 v; float f[4]; uint4 u; };

__device__ __forceinline__ float fsig(float v){ return __builtin_amdgcn_rcpf(1.f+__expf(-v)); }
__device__ __forceinline__ float ftanh(float v){ return 1.f-2.f*__builtin_amdgcn_rcpf(1.f+__expf(2.f*v)); }
// fp16 split-2: v = hi + lo/4096 + O(2^-22 |v|)
__device__ __forceinline__ void split2(float v, f16&h, f16&l){ h=(f16)v; l=(f16)((v-(float)h)*4096.f); }

// bijective XCD-chunking swizzle: blocks on one XCD get contiguous work ids
__device__ __forceinline__ int xcd_swz(int bid, int nwg){
    int q = nwg >> 3, r = nwg & 7;
    int xcd = bid & 7, i = bid >> 3;
    return (xcd < r ? xcd*(q+1) : r*(q+1) + (xcd-r)*q) + i;
}

// ---------------------------------------------------------------------------
// weight [K][N] fp32 -> frag layout ((k>>3)*N + n)*8 + (k&7), hi/lo f16
// ---------------------------------------------------------------------------
__global__ void split_w_kernel(const float* __restrict__ src,
                               f16* __restrict__ dh, f16* __restrict__ dl, int K, int N)
{
    int e = blockIdx.x*256 + threadIdx.x;
    if (e >= K*N) return;
    int k = e / N, n = e - k*N;
    f16 hh, ll; split2(src[e], hh, ll);
    int o = ((k>>3)*N + n)*8 + (k&7);
    dh[o]=hh; dl[o]=ll;
}

// ---------------------------------------------------------------------------
// ht_sum: h-tilde[p] = sum of h over children of p (8 consecutive rows).
// 64 threads per parent row -> fully coalesced 1KB reads per child row.
// ---------------------------------------------------------------------------
__global__ void ht_sum(const float* __restrict__ h, float* __restrict__ ht,
                       int ps, int pe)
{
    int idx = blockIdx.x*256 + threadIdx.x;
    int p = ps + (idx >> 6);
    if (p >= pe) return;
    int dq = (idx & 63) << 2;
    F4 s; s.v = (float4){0,0,0,0};
    int c0 = p*8 + 1;
#pragma unroll
    for (int j = 0; j < 8; ++j) {
        int child = c0 + j;
        if (child < NN) {
            F4 v; v.v = *(const float4*)(h + (size_t)child*256 + dq);
#pragma unroll
            for (int e = 0; e < 4; ++e) s.f[e] += v.f[e];
        }
    }
    *(float4*)(ht + (size_t)(p - ps)*256 + dq) = s.v;
}

// ---------------------------------------------------------------------------
// gemm_iou: K=256 GEMM vs W_iou/U_iou (frag hi/lo, streamed from L2).
// B = fp32 rows, per-lane gather + in-register split. No LDS, no barriers.
// Block = 4 waves sharing one 16-node tile; wave owns 16 cols per gate
// (col-class ct 0..3). Grid = ntiles*4, xcd_swz'd (ct fastest -> same XCD).
//   MODE 0: childless nodes, B=x[node].  Epilogue: full LSTM (fc=0) -> c,h.
//   MODE 1: x_iou precompute, B=x[node]. Store preact + b_iou.
//   MODE 2: internal parents, B=ht[nloc]. Epilogue: LSTM w/ x_iou+fc -> c,h.
// ---------------------------------------------------------------------------
template<int MODE>
__launch_bounds__(256, 4)
__global__ void gemm_iou(const float* __restrict__ bsrc,
                         const f16* __restrict__ wh, const f16* __restrict__ wl,
                         const float* __restrict__ b_iou,
                         const float* __restrict__ xiR, const float* __restrict__ fcR,
                         float* __restrict__ xiW,
                         float* __restrict__ cW, float* __restrict__ hW,
                         int base, int pend)
{
    const int work = xcd_swz(blockIdx.x, gridDim.x);
    const int tile = work >> 2, ct = work & 3;
    const int t = threadIdx.x, lane = t & 63, w = t >> 6;
    const int c15 = lane & 15, qq = lane >> 4;
    const float INV = 1.f/4096.f;

    const int nloc = tile*16 + c15;
    const int node = base + nloc;
    const bool nv = node < pend;
    const size_t brow = (size_t)((MODE == 2) ? nloc : node);
    const float* bp = bsrc + brow*256 + qq*8;
    const int colb = ct*64 + w*16 + c15;

    f32x4 aH0 = (f32x4){0,0,0,0}, aH1 = aH0, aH2 = aH0;
    f32x4 aL0 = aH0, aL1 = aH0, aL2 = aH0;

#pragma unroll
    for (int ch = 0; ch < 8; ++ch) {
        F4 p0, p1; p0.u = (uint4){0,0,0,0}; p1.u = p0.u;
        if (nv) { p0.u = *(const uint4*)(bp + ch*32);
                  p1.u = *(const uint4*)(bp + ch*32 + 4); }
        H8 bh, bl;
#pragma unroll
        for (int e = 0; e < 4; ++e) {
            split2(p0.f[e], bh.f[e],   bl.f[e]);
            split2(p1.f[e], bh.f[4+e], bl.f[4+e]);
        }
        const size_t kb = (size_t)(ch*4 + qq);
        const f16* pa = wh + (kb*768 + colb)*8;
        const f16* pl = wl + (kb*768 + colb)*8;
        f16x8 ah0 = *(const f16x8*)(pa);
        f16x8 ah1 = *(const f16x8*)(pa + 2048);
        f16x8 ah2 = *(const f16x8*)(pa + 4096);
        f16x8 al0 = *(const f16x8*)(pl);
        f16x8 al1 = *(const f16x8*)(pl + 2048);
        f16x8 al2 = *(const f16x8*)(pl + 4096);
        aH0 = MFMA16(ah0, bh.v, aH0); aL0 = MFMA16(ah0, bl.v, aL0); aL0 = MFMA16(al0, bh.v, aL0);
        aH1 = MFMA16(ah1, bh.v, aH1); aL1 = MFMA16(ah1, bl.v, aL1); aL1 = MFMA16(al1, bh.v, aL1);
        aH2 = MFMA16(ah2, bh.v, aH2); aL2 = MFMA16(ah2, bl.v, aL2); aL2 = MFMA16(al2, bh.v, aL2);
    }

    const int d0 = ct*64 + w*16 + qq*4;
    if (MODE == 1) {
        if (nv) {
            F4 b0, b1, b2, o0, o1, o2;
            b0.v = *(const float4*)(b_iou + d0);
            b1.v = *(const float4*)(b_iou + 256 + d0);
            b2.v = *(const float4*)(b_iou + 512 + d0);
#pragma unroll
            for (int j = 0; j < 4; ++j) {
                o0.f[j] = aH0[j] + aL0[j]*INV + b0.f[j];
                o1.f[j] = aH1[j] + aL1[j]*INV + b1.f[j];
                o2.f[j] = aH2[j] + aL2[j]*INV + b2.f[j];
            }
            float* xo = xiW + (size_t)node*768 + d0;
            *(float4*)(xo)       = o0.v;
            *(float4*)(xo + 256) = o1.v;
            *(float4*)(xo + 512) = o2.v;
        }
        return;
    }
    if (!nv) return;
    F4 xi0, xi1, xi2, fcv;
    if (MODE == 0) {
        xi0.v = *(const float4*)(b_iou + d0);
        xi1.v = *(const float4*)(b_iou + 256 + d0);
        xi2.v = *(const float4*)(b_iou + 512 + d0);
        fcv.v = (float4){0,0,0,0};
    } else {
        const float* xr = xiR + (size_t)node*768;
        xi0.v = *(const float4*)(xr + d0);
        xi1.v = *(const float4*)(xr + 256 + d0);
        xi2.v = *(const float4*)(xr + 512 + d0);
        fcv.v = *(const float4*)(fcR + (size_t)nloc*256 + d0);
    }
    F4 cn, hn;
#pragma unroll
    for (int j = 0; j < 4; ++j) {
        float ig = aH0[j] + aL0[j]*INV + xi0.f[j];
        float og = aH1[j] + aL1[j]*INV + xi1.f[j];
        float ug = aH2[j] + aL2[j]*INV + xi2.f[j];
        float cc = fsig(ig)*ftanh(ug) + fcv.f[j];
        cn.f[j] = cc;
        hn.f[j] = fsig(og)*ftanh(cc);
    }
    const size_t no = (size_t)node*256 + d0;
    *(float4*)(cW + no) = cn.v;
    *(float4*)(hW + no) = hn.v;
}

// ---------------------------------------------------------------------------
// gemm_f: K=256 GEMM vs W_f/U_f (frag hi/lo streamed). Tile = 32 nodes
// (two 16-node fragments). Wave owns 16 cols (ct 0..3 covers 256).
//   FMODE 0: xf precompute, B=x[node] (nodes 0..NINT). Store preact + b_f.
//   FMODE 1: child pass, B=h[child]. Epilogue: f=sigm(acc + xf[par]);
//            fc[par] = shfl-sum over sibling group of f*c.
// ---------------------------------------------------------------------------
template<int FMODE>
__launch_bounds__(256, 4)
__global__ void gemm_f(const float* __restrict__ bsrc,
                       const f16* __restrict__ wh, const f16* __restrict__ wl,
                       const float* __restrict__ b_f,
                       const float* __restrict__ xfR, const float* __restrict__ cR,
                       float* __restrict__ xfW, float* __restrict__ fcW,
                       int base, int cend, int pp)
{
    const int work = xcd_swz(blockIdx.x, gridDim.x);
    const int tile = work >> 2, ct = work & 3;
    const int t = threadIdx.x, lane = t & 63, w = t >> 6;
    const int c15 = lane & 15, qq = lane >> 4;
    const float INV = 1.f/4096.f;

    const int n0 = base + tile*32 + c15;
    const int n1 = n0 + 16;
    const bool v0 = n0 < cend, v1 = n1 < cend;
    const float* bp0 = bsrc + (size_t)n0*256 + qq*8;
    const float* bp1 = bsrc + (size_t)n1*256 + qq*8;
    const int colb = ct*64 + w*16 + c15;

    f32x4 aH0 = (f32x4){0,0,0,0}, aH1 = aH0, aL0 = aH0, aL1 = aH0;

#pragma unroll
    for (int ch = 0; ch < 8; ++ch) {
        F4 p0, p1, p2, p3;
        p0.u = (uint4){0,0,0,0}; p1.u = p0.u; p2.u = p0.u; p3.u = p0.u;
        if (v0) { p0.u = *(const uint4*)(bp0 + ch*32); p1.u = *(const uint4*)(bp0 + ch*32 + 4); }
        if (v1) { p2.u = *(const uint4*)(bp1 + ch*32); p3.u = *(const uint4*)(bp1 + ch*32 + 4); }
        H8 bh0, bl0, bh1, bl1;
#pragma unroll
        for (int e = 0; e < 4; ++e) {
            split2(p0.f[e], bh0.f[e],   bl0.f[e]);
            split2(p1.f[e], bh0.f[4+e], bl0.f[4+e]);
            split2(p2.f[e], bh1.f[e],   bl1.f[e]);
            split2(p3.f[e], bh1.f[4+e], bl1.f[4+e]);
        }
        const size_t kb = (size_t)(ch*4 + qq);
        const size_t ao = (kb*256 + colb)*8;
        f16x8 ah = *(const f16x8*)(wh + ao);
        f16x8 al = *(const f16x8*)(wl + ao);
        aH0 = MFMA16(ah, bh0.v, aH0); aL0 = MFMA16(ah, bl0.v, aL0); aL0 = MFMA16(al, bh0.v, aL0);
        aH1 = MFMA16(ah, bh1.v, aH1); aL1 = MFMA16(ah, bl1.v, aL1); aL1 = MFMA16(al, bh1.v, aL1);
    }

    const int d0 = ct*64 + w*16 + qq*4;
    if (FMODE == 0) {
        F4 bf; bf.v = *(const float4*)(b_f + d0);
        if (v0) {
            F4 o;
#pragma unroll
            for (int j = 0; j < 4; ++j) o.f[j] = aH0[j] + aL0[j]*INV + bf.f[j];
            *(float4*)(xfW + (size_t)n0*256 + d0) = o.v;
        }
        if (v1) {
            F4 o;
#pragma unroll
            for (int j = 0; j < 4; ++j) o.f[j] = aH1[j] + aL1[j]*INV + bf.f[j];
            *(float4*)(xfW + (size_t)n1*256 + d0) = o.v;
        }
        return;
    }
    // FMODE 1: fc = sibling-group sum of sigm(preact)*c
    auto fc_epi = [&](int node, bool nv, const f32x4& aH, const f32x4& aL) {
        const int par = (node - 1) >> 3;
        F4 xf4, c4, q;
        xf4.v = (float4){0,0,0,0}; c4 = xf4;
        if (nv) {
            xf4.v = *(const float4*)(xfR + (size_t)par*256 + d0);
            c4.v  = *(const float4*)(cR + (size_t)node*256 + d0);
        }
#pragma unroll
        for (int j = 0; j < 4; ++j) {
            float f = fsig(aH[j] + aL[j]*INV + xf4.f[j]);
            q.f[j] = nv ? f * c4.f[j] : 0.f;
        }
#pragma unroll
        for (int j = 0; j < 4; ++j) {
            q.f[j] += __shfl_xor(q.f[j], 1);
            q.f[j] += __shfl_xor(q.f[j], 2);
            q.f[j] += __shfl_xor(q.f[j], 4);
        }
        if (((c15 & 7) == 0) && nv)
            *(float4*)(fcW + (size_t)(par - pp)*256 + d0) = q.v;
    };
    fc_epi(n0, v0, aH0, aL0);
    fc_epi(n1, v1, aH1, aL1);
}

// ---------------------------------------------------------------------------

extern "C" void kernel_launch(void* const* d_in, const int* in_sizes, int n_in,
                              void* d_out, int out_size, void* d_ws, size_t ws_size,
                              hipStream_t stream)
{
    const float* x     = (const float*)d_in[0];
    const float* W_iou = (const float*)d_in[1];
    const float* U_iou = (const float*)d_in[2];
    const float* b_iou = (const float*)d_in[3];
    const float* W_f   = (const float*)d_in[4];
    const float* U_f   = (const float*)d_in[5];
    const float* b_f   = (const float*)d_in[6];

    float* h = (float*)d_out;

    char* p = (char*)d_ws;
    float* c     = (float*)p;  p += (size_t)NN * 256 * 4;
    float* fc    = (float*)p;  p += (size_t)20320 * 256 * 4;
    float* ht    = (float*)p;  p += (size_t)20320 * 256 * 4;
    float* xf    = (float*)p;  p += (size_t)NINT * 256 * 4;
    float* x_iou = (float*)p;  p += (size_t)NINT * 768 * 4;
    f16* wfh = (f16*)p;  p += 65536  * 2;
    f16* wfl = (f16*)p;  p += 65536  * 2;
    f16* ufh = (f16*)p;  p += 65536  * 2;
    f16* ufl = (f16*)p;  p += 65536  * 2;
    f16* wih = (f16*)p;  p += 196608 * 2;
    f16* wil = (f16*)p;  p += 196608 * 2;
    f16* uih = (f16*)p;  p += 196608 * 2;
    f16* uil = (f16*)p;  p += 196608 * 2;

    split_w_kernel<<<256, 256, 0, stream>>>(W_f,   wfh, wfl, 256, 256);
    split_w_kernel<<<256, 256, 0, stream>>>(U_f,   ufh, ufl, 256, 256);
    split_w_kernel<<<768, 256, 0, stream>>>(W_iou, wih, wil, 256, 768);
    split_w_kernel<<<768, 256, 0, stream>>>(U_iou, uih, uil, 256, 768);

    const int S_[8] = {0, 1, 9, 73, 585, 4681, 37449, 200000};
    auto cdiv = [](int a, int b){ return (a + b - 1) / b; };

    // xf = x @ W_f + b_f for internal nodes (bias folded here)
    gemm_f<0><<<cdiv(NINT,32)*4, 256, 0, stream>>>(
        x, wfh, wfl, b_f, nullptr, nullptr, xf, nullptr, 0, NINT, 0);
    // x_iou = x @ W_iou + b_iou for internal nodes
    gemm_iou<1><<<cdiv(NINT,16)*4, 256, 0, stream>>>(
        x, wih, wil, b_iou, nullptr, nullptr, x_iou, nullptr, nullptr, 0, NINT);
    // all childless nodes: full LSTM with fc = 0.
    // base 24992 (16-aligned): nodes 24992..24999 computed with garbage fc=0,
    // later overwritten by the level-5 parent pass before any reader.
    gemm_iou<0><<<cdiv(NN-24992,16)*4, 256, 0, stream>>>(
        x, wih, wil, b_iou, nullptr, nullptr, nullptr, c, h, 24992, NN);

    // levels 5..0: child fc pass + ht segment-sum, then internal-parent LSTM
    for (int l = 5; l >= 0; --l) {
        int ps = S_[l];
        int pe = (S_[l+1] < NINT) ? S_[l+1] : NINT;
        int cs = S_[l+1], ce = S_[l+2];

        gemm_f<1><<<cdiv(ce-cs,32)*4, 256, 0, stream>>>(
            h, ufh, ufl, nullptr, xf, c, nullptr, fc, cs, ce, ps);
        ht_sum<<<cdiv((pe-ps)*64,256), 256, 0, stream>>>(h, ht, ps, pe);
        gemm_iou<2><<<cdiv(pe-ps,16)*4, 256, 0, stream>>>(
            ht, uih, uil, nullptr, x_iou, fc, nullptr, c, h, ps, pe);
    }
}